// Round 1
// baseline (306.208 us; speedup 1.0000x reference)
//
#include <hip/hip_runtime.h>
#include <hip/hip_bf16.h>
#include <math.h>

// Problem constants (B=1)
#define N_TOK 2048
#define C_DIM 512
#define H_NUM 8
#define DH 64
#define M_LM 64
#define SEG 32
#define KL 4
#define SCALE 0.125f

// ---------------------------------------------------------------------------
// Tiled fp32 GEMM: C[m][j] = sum_k A[m][k] * B[j][k]  (B row-major, i.e. A@B^T)
// 64x64 tile, 256 threads, 4x4 per thread, K-tile 16.
// mode 0: scatter into q/k/v buffers laid out [h][n][d] (for qkv GEMM, J=1536)
// mode 1: out_full[m][j] = acc + bias[j]               (for proj GEMM)
// ---------------------------------------------------------------------------
__global__ __launch_bounds__(256) void gemm_bt(
    const float* __restrict__ A, const float* __restrict__ B, int K,
    float* __restrict__ out_q, float* __restrict__ out_k, float* __restrict__ out_v,
    float* __restrict__ out_full, const float* __restrict__ bias, int ldOut, int mode)
{
  __shared__ float As[16][65];   // [k][m], +1 pad to avoid 16-way bank conflict
  __shared__ float Bs[16][65];   // [k][j]
  int tid = threadIdx.x;
  int tx = tid & 15, ty = tid >> 4;
  int row0 = blockIdx.y << 6;
  int col0 = blockIdx.x << 6;
  float acc[4][4] = {};
  int kk = tid & 15, r0 = tid >> 4;
  for (int k0 = 0; k0 < K; k0 += 16) {
#pragma unroll
    for (int i = 0; i < 4; i++) {
      int r = r0 + (i << 4);
      As[kk][r] = A[(size_t)(row0 + r) * K + k0 + kk];
      Bs[kk][r] = B[(size_t)(col0 + r) * K + k0 + kk];
    }
    __syncthreads();
#pragma unroll
    for (int kk2 = 0; kk2 < 16; kk2++) {
      float a[4], b[4];
#pragma unroll
      for (int i = 0; i < 4; i++) a[i] = As[kk2][(ty << 2) + i];
#pragma unroll
      for (int j = 0; j < 4; j++) b[j] = Bs[kk2][(tx << 2) + j];
#pragma unroll
      for (int i = 0; i < 4; i++)
#pragma unroll
        for (int j = 0; j < 4; j++) acc[i][j] += a[i] * b[j];
    }
    __syncthreads();
  }
  if (mode == 0) {
    // whole 64-wide tile shares one (t,h): col = col0 + d, d in [0,64)
    int t = col0 >> 9;
    int h = (col0 >> 6) & 7;
    float* dst = (t == 0) ? out_q : (t == 1) ? out_k : out_v;
#pragma unroll
    for (int i = 0; i < 4; i++) {
      int n = row0 + (ty << 2) + i;
#pragma unroll
      for (int j = 0; j < 4; j++) {
        int d = (tx << 2) + j;
        dst[(size_t)((h << 11) + n) * DH + d] = acc[i][j];
      }
    }
  } else {
#pragma unroll
    for (int i = 0; i < 4; i++) {
      int rr = row0 + (ty << 2) + i;
#pragma unroll
      for (int j = 0; j < 4; j++) {
        int cc = col0 + (tx << 2) + j;
        out_full[(size_t)rr * ldOut + cc] = acc[i][j] + bias[cc];
      }
    }
  }
}

// ---------------------------------------------------------------------------
// Centroids: cent[h][m][d] = mean over seg of k[h][m*32+s][d]
// ---------------------------------------------------------------------------
__global__ void centroid_kernel(const float* __restrict__ kb, float* __restrict__ cent)
{
  int idx = blockIdx.x * blockDim.x + threadIdx.x;  // 8*64*64 = 32768
  int d = idx & 63;
  int m = (idx >> 6) & 63;
  int h = idx >> 12;
  const float* base = kb + ((size_t)(h << 11) + m * SEG) * DH + d;
  float s = 0.f;
#pragma unroll
  for (int ss = 0; ss < SEG; ss++) s += base[(size_t)ss * DH];
  cent[idx] = s * (1.0f / SEG);
}

// ---------------------------------------------------------------------------
// Route + top-4 (jax tie-break: lower index wins on equal value).
// 4 queries per 256-thread block, one wave (64 lanes) per query.
// ---------------------------------------------------------------------------
__global__ __launch_bounds__(256) void route_topk_kernel(
    const float* __restrict__ qb, const float* __restrict__ cent, int* __restrict__ topk)
{
  int wave = threadIdx.x >> 6;
  int lane = threadIdx.x & 63;
  int qi = (blockIdx.x << 2) + wave;  // h*2048 + n
  int h = qi >> 11;
  __shared__ float qs[4][64];
  qs[wave][lane] = qb[(size_t)qi * DH + lane];
  __syncthreads();
  const float* c = cent + ((size_t)(h << 6) + lane) * DH;
  float dot = 0.f;
#pragma unroll
  for (int d = 0; d < DH; d++) dot += qs[wave][d] * c[d];
  float val = dot * SCALE;
  for (int r = 0; r < KL; r++) {
    float v = val;
    int id = lane;
#pragma unroll
    for (int off = 32; off; off >>= 1) {
      float ov = __shfl_xor(v, off, 64);
      int oi = __shfl_xor(id, off, 64);
      if (ov > v || (ov == v && oi < id)) { v = ov; id = oi; }
    }
    if (lane == 0) topk[qi * KL + r] = id;
    if (lane == id) val = -INFINITY;
  }
}

// ---------------------------------------------------------------------------
// Sparse attention: per query, 4 segments x 32 keys = 128 keys, Dh=64.
// One wave per query; lane scores keys (lane, lane+64); shuffle softmax;
// output: lane = d, coalesced accumulation over V rows.
// attn_out laid out (N, C): attn_out[n][h*64+d]
// ---------------------------------------------------------------------------
__global__ __launch_bounds__(256) void attn_kernel(
    const float* __restrict__ qb, const float* __restrict__ kb,
    const float* __restrict__ vb, const int* __restrict__ topk,
    float* __restrict__ attn_out)
{
  int wave = threadIdx.x >> 6;
  int lane = threadIdx.x & 63;
  int qi = (blockIdx.x << 2) + wave;
  int h = qi >> 11, n = qi & 2047;
  __shared__ float qs[4][64];
  __shared__ float probs[4][128];
  __shared__ int segs[4][4];
  qs[wave][lane] = qb[(size_t)qi * DH + lane];
  if (lane < KL) segs[wave][lane] = topk[qi * KL + lane];
  __syncthreads();

  float sc[2];
#pragma unroll
  for (int t = 0; t < 2; t++) {
    int j = lane + (t << 6);
    int key_n = segs[wave][j >> 5] * SEG + (j & 31);
    const float4* kr = (const float4*)(kb + ((size_t)(h << 11) + key_n) * DH);
    const float4* qv = (const float4*)qs[wave];
    float dot = 0.f;
#pragma unroll
    for (int d4 = 0; d4 < 16; d4++) {
      float4 a = qv[d4], b = kr[d4];
      dot += a.x * b.x + a.y * b.y + a.z * b.z + a.w * b.w;
    }
    sc[t] = dot * SCALE;
  }
  float mx = fmaxf(sc[0], sc[1]);
#pragma unroll
  for (int off = 32; off; off >>= 1) mx = fmaxf(mx, __shfl_xor(mx, off, 64));
  float e0 = expf(sc[0] - mx), e1 = expf(sc[1] - mx);
  float s = e0 + e1;
#pragma unroll
  for (int off = 32; off; off >>= 1) s += __shfl_xor(s, off, 64);
  float inv = 1.0f / s;
  probs[wave][lane] = e0 * inv;
  probs[wave][lane + 64] = e1 * inv;
  __syncthreads();

  float o = 0.f;
#pragma unroll
  for (int si = 0; si < KL; si++) {
    int seg = segs[wave][si];
    const float* vrow = vb + ((size_t)(h << 11) + seg * SEG) * DH + lane;
#pragma unroll
    for (int ss = 0; ss < SEG; ss++) o += probs[wave][(si << 5) + ss] * vrow[(size_t)ss * DH];
  }
  attn_out[(size_t)n * C_DIM + (h << 6) + lane] = o;
}

// ---------------------------------------------------------------------------
extern "C" void kernel_launch(void* const* d_in, const int* in_sizes, int n_in,
                              void* d_out, int out_size, void* d_ws, size_t ws_size,
                              hipStream_t stream)
{
  const float* x      = (const float*)d_in[0];   // (1,2048,512)
  const float* w_qkv  = (const float*)d_in[1];   // (1536,512)
  const float* w_proj = (const float*)d_in[2];   // (512,512)
  const float* b_proj = (const float*)d_in[3];   // (512,)
  float* out = (float*)d_out;                    // (1,2048,512)

  float* ws = (float*)d_ws;
  float* qbuf = ws;                          // [8][2048][64]
  float* kbuf = qbuf + (size_t)H_NUM * N_TOK * DH;
  float* vbuf = kbuf + (size_t)H_NUM * N_TOK * DH;
  float* attn_out = vbuf + (size_t)H_NUM * N_TOK * DH;   // [2048][512]
  float* cent = attn_out + (size_t)N_TOK * C_DIM;        // [8][64][64]
  int* topk = (int*)(cent + (size_t)H_NUM * M_LM * DH);  // [8][2048][4]

  // 1. QKV GEMM: (2048 x 512) @ (1536 x 512)^T, scatter to q/k/v [h][n][d]
  {
    dim3 grid(1536 / 64, N_TOK / 64);
    gemm_bt<<<grid, 256, 0, stream>>>(x, w_qkv, C_DIM, qbuf, kbuf, vbuf,
                                      nullptr, nullptr, 0, 0);
  }
  // 2. centroids
  centroid_kernel<<<(H_NUM * M_LM * DH) / 256, 256, 0, stream>>>(kbuf, cent);
  // 3. route + top-4
  route_topk_kernel<<<(H_NUM * N_TOK) / 4, 256, 0, stream>>>(qbuf, cent, topk);
  // 4. sparse attention
  attn_kernel<<<(H_NUM * N_TOK) / 4, 256, 0, stream>>>(qbuf, kbuf, vbuf, topk, attn_out);
  // 5. proj GEMM + bias: (2048 x 512) @ (512 x 512)^T + b
  {
    dim3 grid(C_DIM / 64, N_TOK / 64);
    gemm_bt<<<grid, 256, 0, stream>>>(attn_out, w_proj, C_DIM, nullptr, nullptr,
                                      nullptr, out, b_proj, C_DIM, 1);
  }
}

// Round 4
// 225.701 us; speedup vs baseline: 1.3567x; 1.3567x over previous
//
#include <hip/hip_runtime.h>
#include <hip/hip_bf16.h>
#include <math.h>

#define N_TOK 2048
#define C_DIM 512
#define H_NUM 8
#define DH 64
#define M_LM 64
#define SEG 32
#define KL 4
#define SCALE 0.125f

typedef __attribute__((ext_vector_type(8))) short short8;
typedef __attribute__((ext_vector_type(4))) float f32x4;

__device__ inline unsigned short f2bf(float f) {
  unsigned u = __float_as_uint(f);
  u += 0x7FFF + ((u >> 16) & 1);
  return (unsigned short)(u >> 16);
}
__device__ inline float bf2f(unsigned short h) {
  return __uint_as_float(((unsigned)h) << 16);
}

// ---------------------------------------------------------------------------
// fp32 tiled GEMM — BYTE-IDENTICAL source to R0's gemm_bt. Used ONLY for the
// Q/K columns (col0 < 1024) so q,k (and hence centroids/route/topk) are
// bit-identical to the R0 run that passed. Do not touch this kernel.
// ---------------------------------------------------------------------------
__global__ __launch_bounds__(256) void gemm_bt(
    const float* __restrict__ A, const float* __restrict__ B, int K,
    float* __restrict__ out_q, float* __restrict__ out_k, float* __restrict__ out_v,
    float* __restrict__ out_full, const float* __restrict__ bias, int ldOut, int mode)
{
  __shared__ float As[16][65];   // [k][m], +1 pad to avoid 16-way bank conflict
  __shared__ float Bs[16][65];   // [k][j]
  int tid = threadIdx.x;
  int tx = tid & 15, ty = tid >> 4;
  int row0 = blockIdx.y << 6;
  int col0 = blockIdx.x << 6;
  float acc[4][4] = {};
  int kk = tid & 15, r0 = tid >> 4;
  for (int k0 = 0; k0 < K; k0 += 16) {
#pragma unroll
    for (int i = 0; i < 4; i++) {
      int r = r0 + (i << 4);
      As[kk][r] = A[(size_t)(row0 + r) * K + k0 + kk];
      Bs[kk][r] = B[(size_t)(col0 + r) * K + k0 + kk];
    }
    __syncthreads();
#pragma unroll
    for (int kk2 = 0; kk2 < 16; kk2++) {
      float a[4], b[4];
#pragma unroll
      for (int i = 0; i < 4; i++) a[i] = As[kk2][(ty << 2) + i];
#pragma unroll
      for (int j = 0; j < 4; j++) b[j] = Bs[kk2][(tx << 2) + j];
#pragma unroll
      for (int i = 0; i < 4; i++)
#pragma unroll
        for (int j = 0; j < 4; j++) acc[i][j] += a[i] * b[j];
    }
    __syncthreads();
  }
  if (mode == 0) {
    int t = col0 >> 9;
    int h = (col0 >> 6) & 7;
    float* dst = (t == 0) ? out_q : (t == 1) ? out_k : out_v;
#pragma unroll
    for (int i = 0; i < 4; i++) {
      int n = row0 + (ty << 2) + i;
#pragma unroll
      for (int j = 0; j < 4; j++) {
        int d = (tx << 2) + j;
        dst[(size_t)((h << 11) + n) * DH + d] = acc[i][j];
      }
    }
  } else {
#pragma unroll
    for (int i = 0; i < 4; i++) {
      int rr = row0 + (ty << 2) + i;
#pragma unroll
      for (int j = 0; j < 4; j++) {
        int cc = col0 + (tx << 2) + j;
        out_full[(size_t)rr * ldOut + cc] = acc[i][j] + bias[cc];
      }
    }
  }
}

// ---------------------------------------------------------------------------
// Split fp32 -> bf16 2-term (hi|lo), dst row stride 1024.
// ---------------------------------------------------------------------------
__global__ void split_kernel(const float* __restrict__ src, unsigned short* __restrict__ dst)
{
  int idx = blockIdx.x * 256 + threadIdx.x;
  int r = idx >> 9, k = idx & 511;
  float a = src[idx];
  unsigned short h1 = f2bf(a);
  float r1 = a - bf2f(h1);
  dst[(size_t)(r << 10) + k] = h1;
  dst[(size_t)(r << 10) + 512 + k] = f2bf(r1);
}

// ---------------------------------------------------------------------------
// bf16-split MFMA GEMM, 3 products: Ahi.Bhi + Alo.Bhi + Ahi.Blo (2^-18 rel).
// A2: M x 1024 (hi|lo), B2: N x 1024.  64x64 tile, 4 waves 2x2, each wave
// 32x32 via 2x2 mfma_f32_16x16x32_bf16.
// mode 0: V-scatter  vbuf[(h<<11)+row][d],  h=(col0>>6)&7, d=col&63
// mode 1: ofull[row][col] = acc + bias[col]
// ---------------------------------------------------------------------------
__global__ __launch_bounds__(256) void gemm_mfma(
    const unsigned short* __restrict__ A2, const unsigned short* __restrict__ B2,
    float* __restrict__ ov, float* __restrict__ ofull,
    const float* __restrict__ bias, int ldout, int mode)
{
  // LDS: element (m,k) at [(k>>3)*64 + m]*8 + (k&7)
  __shared__ short Al[4096];
  __shared__ short Bl[4096];
  int tid = threadIdx.x;
  int lane = tid & 63, w = tid >> 6;
  int row0 = blockIdx.y << 6, col0 = blockIdx.x << 6;
  int wr = (w >> 1) * 32, wc = (w & 1) * 32;
  int m_lo = tid & 7, h8 = (tid >> 3) & 7, m_hi = tid >> 6;
  int ms = m_hi * 8 + m_lo;  // 0..31
  int q = lane >> 4, ln = lane & 15;

  f32x4 acc[2][2];
#pragma unroll
  for (int mi = 0; mi < 2; mi++)
#pragma unroll
    for (int ni = 0; ni < 2; ni++)
#pragma unroll
      for (int r = 0; r < 4; r++) acc[mi][ni][r] = 0.0f;

  for (int s = 0; s < 24; s++) {
    int ka = (s < 8) ? s * 64 : (s < 16) ? 512 + (s - 8) * 64 : (s - 16) * 64;
    int kb = (s < 8) ? s * 64 : (s < 16) ? (s - 8) * 64 : 512 + (s - 16) * 64;
    short8 a0 = *(const short8*)(A2 + (size_t)(row0 + ms) * 1024 + ka + h8 * 8);
    short8 a1 = *(const short8*)(A2 + (size_t)(row0 + ms + 32) * 1024 + ka + h8 * 8);
    short8 b0 = *(const short8*)(B2 + (size_t)(col0 + ms) * 1024 + kb + h8 * 8);
    short8 b1 = *(const short8*)(B2 + (size_t)(col0 + ms + 32) * 1024 + kb + h8 * 8);
    __syncthreads();
    *(short8*)&Al[(h8 * 64 + ms) * 8] = a0;
    *(short8*)&Al[(h8 * 64 + ms + 32) * 8] = a1;
    *(short8*)&Bl[(h8 * 64 + ms) * 8] = b0;
    *(short8*)&Bl[(h8 * 64 + ms + 32) * 8] = b1;
    __syncthreads();
    short8 af[2][2], bf[2][2];
#pragma unroll
    for (int sub = 0; sub < 2; sub++)
#pragma unroll
      for (int i = 0; i < 2; i++) {
        af[sub][i] = *(const short8*)&Al[((sub * 4 + q) * 64 + wr + i * 16 + ln) * 8];
        bf[sub][i] = *(const short8*)&Bl[((sub * 4 + q) * 64 + wc + i * 16 + ln) * 8];
      }
#pragma unroll
    for (int sub = 0; sub < 2; sub++)
#pragma unroll
      for (int mi = 0; mi < 2; mi++)
#pragma unroll
        for (int ni = 0; ni < 2; ni++)
          acc[mi][ni] = __builtin_amdgcn_mfma_f32_16x16x32_bf16(
              af[sub][mi], bf[sub][ni], acc[mi][ni], 0, 0, 0);
  }

  // C row = row0 + wr + mi*16 + q*4 + r, col = col0 + wc + ni*16 + ln
  if (mode == 0) {
    int hh = (col0 >> 6) & 7;
#pragma unroll
    for (int mi = 0; mi < 2; mi++)
#pragma unroll
      for (int ni = 0; ni < 2; ni++)
#pragma unroll
        for (int r = 0; r < 4; r++) {
          int row = row0 + wr + mi * 16 + q * 4 + r;
          int d = wc + ni * 16 + ln;
          ov[(size_t)((hh << 11) + row) * DH + d] = acc[mi][ni][r];
        }
  } else {
#pragma unroll
    for (int mi = 0; mi < 2; mi++)
#pragma unroll
      for (int ni = 0; ni < 2; ni++)
#pragma unroll
        for (int r = 0; r < 4; r++) {
          int row = row0 + wr + mi * 16 + q * 4 + r;
          int col = col0 + wc + ni * 16 + ln;
          ofull[(size_t)row * ldout + col] = acc[mi][ni][r] + bias[col];
        }
  }
}

// ---------------------------------------------------------------------------
// Centroids (byte-identical to R0): cent[h][m][d] = mean_s k[h][m*32+s][d]
// ---------------------------------------------------------------------------
__global__ void centroid_kernel(const float* __restrict__ kb, float* __restrict__ cent)
{
  int idx = blockIdx.x * blockDim.x + threadIdx.x;  // 32768
  int m = (idx >> 6) & 63;
  int h = idx >> 12;
  int d = idx & 63;
  const float* base = kb + ((size_t)(h << 11) + m * SEG) * DH + d;
  float s = 0.f;
#pragma unroll
  for (int ss = 0; ss < SEG; ss++) s += base[(size_t)ss * DH];
  cent[idx] = s * (1.0f / SEG);
}

// ---------------------------------------------------------------------------
// Route + top-4. Dot is d-ascending sequential — same value order as R0, so
// with bit-identical q,cent the scores and topk are bit-identical to R0.
// ---------------------------------------------------------------------------
__global__ __launch_bounds__(256) void route_topk_kernel(
    const float* __restrict__ qb, const float* __restrict__ cent, int* __restrict__ topk)
{
  __shared__ float centT[64][65];
  __shared__ float qs[4][64];
  int tid = threadIdx.x;
  int wave = tid >> 6, lane = tid & 63;
  int qi = (blockIdx.x << 2) + wave;
  int h = qi >> 11;  // uniform across block
  qs[wave][lane] = qb[(size_t)qi * DH + lane];
  const float4* c4 = (const float4*)(cent + ((size_t)h << 12));
#pragma unroll
  for (int i = 0; i < 4; i++) {
    int f4 = tid + 256 * i;       // 0..1023
    int m = f4 >> 4;
    int d0 = (f4 & 15) * 4;
    float4 v = c4[f4];
    centT[d0][m] = v.x; centT[d0 + 1][m] = v.y;
    centT[d0 + 2][m] = v.z; centT[d0 + 3][m] = v.w;
  }
  __syncthreads();
  float dot = 0.f;
#pragma unroll
  for (int d = 0; d < 64; d++) dot += qs[wave][d] * centT[d][lane];
  float val = dot * SCALE;
  for (int r = 0; r < KL; r++) {
    float v = val;
    int id = lane;
#pragma unroll
    for (int off = 32; off; off >>= 1) {
      float ov = __shfl_xor(v, off, 64);
      int oi = __shfl_xor(id, off, 64);
      if (ov > v || (ov == v && oi < id)) { v = ov; id = oi; }
    }
    if (lane == 0) topk[qi * KL + r] = id;
    if (lane == id) val = -INFINITY;
  }
}

// ---------------------------------------------------------------------------
// Sparse attention, line-sharing K loads: lane = (row%16)*4 + chunk.
// Output written as 2-term bf16 split (stride 1024) for the proj GEMM.
// ---------------------------------------------------------------------------
__global__ __launch_bounds__(256) void attn_kernel(
    const float* __restrict__ qb, const float* __restrict__ kb,
    const float* __restrict__ vb, const int* __restrict__ topk,
    unsigned short* __restrict__ ao2)
{
  __shared__ float probs[4][128];
  int tid = threadIdx.x;
  int wave = tid >> 6, lane = tid & 63;
  int qi = (blockIdx.x << 2) + wave;
  int h = qi >> 11, n = qi & 2047;
  int4 tk = *(const int4*)(topk + qi * KL);
  int segArr[4] = {tk.x, tk.y, tk.z, tk.w};
  const float* qrow = qb + (size_t)qi * DH;
  float4 qreg[4];
#pragma unroll
  for (int i = 0; i < 4; i++)
    qreg[i] = *(const float4*)(qrow + ((lane & 3) + 4 * i) * 4);

  float e[8];
  float score[8];
#pragma unroll
  for (int g = 0; g < 8; g++) {
    int seg = segArr[g >> 1];
    int key_n = seg * SEG + (lane >> 2) + 16 * (g & 1);
    const float* krow = kb + ((size_t)(h << 11) + key_n) * DH;
    float acc = 0.f;
#pragma unroll
    for (int i = 0; i < 4; i++) {
      float4 kv = *(const float4*)(krow + ((lane & 3) + 4 * i) * 4);
      float4 qv = qreg[i];
      acc += qv.x * kv.x + qv.y * kv.y + qv.z * kv.z + qv.w * kv.w;
    }
    acc += __shfl_xor(acc, 1, 64);
    acc += __shfl_xor(acc, 2, 64);
    score[g] = acc * SCALE;
  }
  float mx = score[0];
#pragma unroll
  for (int g = 1; g < 8; g++) mx = fmaxf(mx, score[g]);
#pragma unroll
  for (int off = 4; off < 64; off <<= 1) mx = fmaxf(mx, __shfl_xor(mx, off, 64));
  float ls = 0.f;
#pragma unroll
  for (int g = 0; g < 8; g++) { e[g] = expf(score[g] - mx); ls += e[g]; }
#pragma unroll
  for (int off = 4; off < 64; off <<= 1) ls += __shfl_xor(ls, off, 64);
  float inv = 1.0f / ls;
  if ((lane & 3) == 0) {
#pragma unroll
    for (int g = 0; g < 8; g++) probs[wave][(lane >> 2) + 16 * g] = e[g] * inv;
  }
  __syncthreads();

  float o = 0.f;
#pragma unroll
  for (int si = 0; si < KL; si++) {
    int seg = segArr[si];
    const float* vrow = vb + ((size_t)(h << 11) + seg * SEG) * DH + lane;
#pragma unroll
    for (int ss = 0; ss < SEG; ss++) o += probs[wave][(si << 5) + ss] * vrow[(size_t)ss * DH];
  }
  unsigned short hb = f2bf(o);
  float lo = o - bf2f(hb);
  ao2[(size_t)n * 1024 + (h << 6) + lane] = hb;
  ao2[(size_t)n * 1024 + 512 + (h << 6) + lane] = f2bf(lo);
}

// ---------------------------------------------------------------------------
extern "C" void kernel_launch(void* const* d_in, const int* in_sizes, int n_in,
                              void* d_out, int out_size, void* d_ws, size_t ws_size,
                              hipStream_t stream)
{
  const float* x      = (const float*)d_in[0];   // (1,2048,512)
  const float* w_qkv  = (const float*)d_in[1];   // (1536,512)
  const float* w_proj = (const float*)d_in[2];   // (512,512)
  const float* b_proj = (const float*)d_in[3];   // (512,)
  float* out = (float*)d_out;                    // (1,2048,512)

  float* base = (float*)d_ws;
  float* qbuf = base;                                   // 1,048,576 f
  float* kbuf = base + 1048576;
  float* vbuf = base + 2097152;
  float* cent = base + 3145728;                         // 32,768 f
  int*   topk = (int*)(base + 3178496);                 // 65,536 i
  unsigned short* X2  = (unsigned short*)(base + 3244032);  // 2048x1024 bf16 (2-term)
  unsigned short* W2v = (unsigned short*)(base + 4292608);  // 512x1024  (V rows of w_qkv)
  unsigned short* WP2 = (unsigned short*)(base + 4554752);  // 512x1024  (w_proj)
  unsigned short* AO2 = X2;  // overlay: X2 dead after V GEMM

  // 1. 2-term bf16 splits for the continuous-path MFMA GEMMs
  split_kernel<<<(2048 * 512) / 256, 256, 0, stream>>>(x, X2);
  split_kernel<<<(512 * 512) / 256, 256, 0, stream>>>(w_qkv + 1024 * 512, W2v);
  split_kernel<<<(512 * 512) / 256, 256, 0, stream>>>(w_proj, WP2);

  // 2. Q/K via fp32 gemm_bt — bit-identical to the R0 run (route path frozen)
  {
    dim3 grid(1024 / 64, N_TOK / 64);   // cols 0..1023 = Q,K only
    gemm_bt<<<grid, 256, 0, stream>>>(x, w_qkv, C_DIM, qbuf, kbuf, nullptr,
                                      nullptr, nullptr, 0, 0);
  }
  // 3. V via bf16-split MFMA (continuous path)
  {
    dim3 grid(512 / 64, N_TOK / 64);
    gemm_mfma<<<grid, 256, 0, stream>>>(X2, W2v, vbuf, nullptr, nullptr, 0, 0);
  }
  // 4. centroids (from bit-exact k)
  centroid_kernel<<<(H_NUM * M_LM * DH) / 256, 256, 0, stream>>>(kbuf, cent);
  // 5. route + top-4 (bit-exact scores vs R0)
  route_topk_kernel<<<(H_NUM * N_TOK) / 4, 256, 0, stream>>>(qbuf, cent, topk);
  // 6. sparse attention -> 2-term AO2 (overlays X2)
  attn_kernel<<<(H_NUM * N_TOK) / 4, 256, 0, stream>>>(qbuf, kbuf, vbuf, topk, AO2);
  // 7. proj GEMM (MFMA, 3 products) + bias
  {
    dim3 grid(C_DIM / 64, N_TOK / 64);
    gemm_mfma<<<grid, 256, 0, stream>>>(AO2, WP2, nullptr, out, b_proj, C_DIM, 1);
  }
}

// Round 5
// 209.684 us; speedup vs baseline: 1.4603x; 1.0764x over previous
//
#include <hip/hip_runtime.h>
#include <hip/hip_bf16.h>
#include <math.h>

#define N_TOK 2048
#define C_DIM 512
#define H_NUM 8
#define DH 64
#define M_LM 64
#define SEG 32
#define KL 4
#define SCALE 0.125f

typedef __attribute__((ext_vector_type(8))) short short8;
typedef __attribute__((ext_vector_type(4))) float f32x4;

__device__ inline unsigned short f2bf(float f) {
  unsigned u = __float_as_uint(f);
  u += 0x7FFF + ((u >> 16) & 1);
  return (unsigned short)(u >> 16);
}
__device__ inline float bf2f(unsigned short h) {
  return __uint_as_float(((unsigned)h) << 16);
}

// ---------------------------------------------------------------------------
// Q/K fp32 GEMM, restructured memory path but bit-identical arithmetic to
// R0's gemm_bt: per output, acc[i][j] += a[i]*b[j] over k=0..511 ascending,
// same expression (same contraction). LDS rows padded to 68 floats so
// fragments load as ds_read_b128; k-tile 32; register-prefetch next tile.
// cols [0,1024): t=col0>>9 (0=Q,1=K), h=(col0>>6)&7, scatter [h][n][d].
// ---------------------------------------------------------------------------
__global__ __launch_bounds__(256) void gemm_qk(
    const float* __restrict__ A, const float* __restrict__ B,
    float* __restrict__ out_q, float* __restrict__ out_k)
{
  __shared__ float As[32][68];   // [k][m], pad->16B-aligned rows, bank shift 4
  __shared__ float Bs[32][68];   // [k][j]
  int tid = threadIdx.x;
  int tx = tid & 15, ty = tid >> 4;
  int row0 = blockIdx.y << 6;
  int col0 = blockIdx.x << 6;
  float acc[4][4] = {};
  int kk = tid & 31, rr = tid >> 5;   // staging: 32 k-cols x 8 row-groups

  float pa[8], pb[8];
#pragma unroll
  for (int i = 0; i < 8; i++) {
    pa[i] = A[(size_t)(row0 + rr + i * 8) * 512 + kk];
    pb[i] = B[(size_t)(col0 + rr + i * 8) * 512 + kk];
  }

  for (int k0 = 0; k0 < 512; k0 += 32) {
    __syncthreads();
#pragma unroll
    for (int i = 0; i < 8; i++) {
      As[kk][rr + i * 8] = pa[i];
      Bs[kk][rr + i * 8] = pb[i];
    }
    __syncthreads();
    if (k0 + 32 < 512) {
#pragma unroll
      for (int i = 0; i < 8; i++) {
        pa[i] = A[(size_t)(row0 + rr + i * 8) * 512 + k0 + 32 + kk];
        pb[i] = B[(size_t)(col0 + rr + i * 8) * 512 + k0 + 32 + kk];
      }
    }
#pragma unroll
    for (int kk2 = 0; kk2 < 32; kk2++) {
      float a[4], b[4];
      *(float4*)a = *(const float4*)&As[kk2][ty << 2];
      *(float4*)b = *(const float4*)&Bs[kk2][tx << 2];
#pragma unroll
      for (int i = 0; i < 4; i++)
#pragma unroll
        for (int j = 0; j < 4; j++) acc[i][j] += a[i] * b[j];
    }
  }

  int t = col0 >> 9;
  int h = (col0 >> 6) & 7;
  float* dst = (t == 0) ? out_q : out_k;
#pragma unroll
  for (int i = 0; i < 4; i++) {
    int n = row0 + (ty << 2) + i;
#pragma unroll
    for (int j = 0; j < 4; j++) {
      int d = (tx << 2) + j;
      dst[(size_t)((h << 11) + n) * DH + d] = acc[i][j];
    }
  }
}

// ---------------------------------------------------------------------------
// Fused 2-term bf16 splits for x (rows 2048), w_qkv V-rows (512), w_proj (512).
// ---------------------------------------------------------------------------
__global__ void split3_kernel(const float* __restrict__ x, const float* __restrict__ wv,
                              const float* __restrict__ wp,
                              unsigned short* __restrict__ X2,
                              unsigned short* __restrict__ W2v,
                              unsigned short* __restrict__ WP2)
{
  int idx = blockIdx.x * 256 + threadIdx.x;   // 0 .. 1572863
  const float* src; unsigned short* dst; int li;
  if (idx < 1048576)      { src = x;  dst = X2;  li = idx; }
  else if (idx < 1310720) { src = wv; dst = W2v; li = idx - 1048576; }
  else                    { src = wp; dst = WP2; li = idx - 1310720; }
  int r = li >> 9, k = li & 511;
  float a = src[li];
  unsigned short h1 = f2bf(a);
  float r1 = a - bf2f(h1);
  dst[(size_t)(r << 10) + k] = h1;
  dst[(size_t)(r << 10) + 512 + k] = f2bf(r1);
}

// ---------------------------------------------------------------------------
// bf16-split MFMA GEMM, 3 products: Ahi.Bhi + Alo.Bhi + Ahi.Blo (2^-18 rel).
// A2: M x 1024 (hi|lo), B2: N x 1024.  64x64 tile, 4 waves 2x2, each wave
// 32x32 via 2x2 mfma_f32_16x16x32_bf16.
// mode 0: V-scatter  vbuf[(h<<11)+row][d];  mode 1: ofull = acc + bias.
// ---------------------------------------------------------------------------
__global__ __launch_bounds__(256) void gemm_mfma(
    const unsigned short* __restrict__ A2, const unsigned short* __restrict__ B2,
    float* __restrict__ ov, float* __restrict__ ofull,
    const float* __restrict__ bias, int ldout, int mode)
{
  __shared__ short Al[4096];
  __shared__ short Bl[4096];
  int tid = threadIdx.x;
  int lane = tid & 63, w = tid >> 6;
  int row0 = blockIdx.y << 6, col0 = blockIdx.x << 6;
  int wr = (w >> 1) * 32, wc = (w & 1) * 32;
  int m_lo = tid & 7, h8 = (tid >> 3) & 7, m_hi = tid >> 6;
  int ms = m_hi * 8 + m_lo;  // 0..31
  int q = lane >> 4, ln = lane & 15;

  f32x4 acc[2][2];
#pragma unroll
  for (int mi = 0; mi < 2; mi++)
#pragma unroll
    for (int ni = 0; ni < 2; ni++)
#pragma unroll
      for (int r = 0; r < 4; r++) acc[mi][ni][r] = 0.0f;

  for (int s = 0; s < 24; s++) {
    int ka = (s < 8) ? s * 64 : (s < 16) ? 512 + (s - 8) * 64 : (s - 16) * 64;
    int kb = (s < 8) ? s * 64 : (s < 16) ? (s - 8) * 64 : 512 + (s - 16) * 64;
    short8 a0 = *(const short8*)(A2 + (size_t)(row0 + ms) * 1024 + ka + h8 * 8);
    short8 a1 = *(const short8*)(A2 + (size_t)(row0 + ms + 32) * 1024 + ka + h8 * 8);
    short8 b0 = *(const short8*)(B2 + (size_t)(col0 + ms) * 1024 + kb + h8 * 8);
    short8 b1 = *(const short8*)(B2 + (size_t)(col0 + ms + 32) * 1024 + kb + h8 * 8);
    __syncthreads();
    *(short8*)&Al[(h8 * 64 + ms) * 8] = a0;
    *(short8*)&Al[(h8 * 64 + ms + 32) * 8] = a1;
    *(short8*)&Bl[(h8 * 64 + ms) * 8] = b0;
    *(short8*)&Bl[(h8 * 64 + ms + 32) * 8] = b1;
    __syncthreads();
    short8 af[2][2], bf[2][2];
#pragma unroll
    for (int sub = 0; sub < 2; sub++)
#pragma unroll
      for (int i = 0; i < 2; i++) {
        af[sub][i] = *(const short8*)&Al[((sub * 4 + q) * 64 + wr + i * 16 + ln) * 8];
        bf[sub][i] = *(const short8*)&Bl[((sub * 4 + q) * 64 + wc + i * 16 + ln) * 8];
      }
#pragma unroll
    for (int sub = 0; sub < 2; sub++)
#pragma unroll
      for (int mi = 0; mi < 2; mi++)
#pragma unroll
        for (int ni = 0; ni < 2; ni++)
          acc[mi][ni] = __builtin_amdgcn_mfma_f32_16x16x32_bf16(
              af[sub][mi], bf[sub][ni], acc[mi][ni], 0, 0, 0);
  }

  if (mode == 0) {
    int hh = (col0 >> 6) & 7;
#pragma unroll
    for (int mi = 0; mi < 2; mi++)
#pragma unroll
      for (int ni = 0; ni < 2; ni++)
#pragma unroll
        for (int r = 0; r < 4; r++) {
          int row = row0 + wr + mi * 16 + q * 4 + r;
          int d = wc + ni * 16 + ln;
          ov[(size_t)((hh << 11) + row) * DH + d] = acc[mi][ni][r];
        }
  } else {
#pragma unroll
    for (int mi = 0; mi < 2; mi++)
#pragma unroll
      for (int ni = 0; ni < 2; ni++)
#pragma unroll
        for (int r = 0; r < 4; r++) {
          int row = row0 + wr + mi * 16 + q * 4 + r;
          int col = col0 + wc + ni * 16 + ln;
          ofull[(size_t)row * ldout + col] = acc[mi][ni][r] + bias[col];
        }
  }
}

// ---------------------------------------------------------------------------
// Centroids (byte-identical to R0): cent[h][m][d] = mean_s k[h][m*32+s][d]
// ---------------------------------------------------------------------------
__global__ void centroid_kernel(const float* __restrict__ kb, float* __restrict__ cent)
{
  int idx = blockIdx.x * blockDim.x + threadIdx.x;  // 32768
  int m = (idx >> 6) & 63;
  int h = idx >> 12;
  int d = idx & 63;
  const float* base = kb + ((size_t)(h << 11) + m * SEG) * DH + d;
  float s = 0.f;
#pragma unroll
  for (int ss = 0; ss < SEG; ss++) s += base[(size_t)ss * DH];
  cent[idx] = s * (1.0f / SEG);
}

// ---------------------------------------------------------------------------
// Route + top-4 (byte-identical to R4's passing version).
// ---------------------------------------------------------------------------
__global__ __launch_bounds__(256) void route_topk_kernel(
    const float* __restrict__ qb, const float* __restrict__ cent, int* __restrict__ topk)
{
  __shared__ float centT[64][65];
  __shared__ float qs[4][64];
  int tid = threadIdx.x;
  int wave = tid >> 6, lane = tid & 63;
  int qi = (blockIdx.x << 2) + wave;
  int h = qi >> 11;  // uniform across block
  qs[wave][lane] = qb[(size_t)qi * DH + lane];
  const float4* c4 = (const float4*)(cent + ((size_t)h << 12));
#pragma unroll
  for (int i = 0; i < 4; i++) {
    int f4 = tid + 256 * i;       // 0..1023
    int m = f4 >> 4;
    int d0 = (f4 & 15) * 4;
    float4 v = c4[f4];
    centT[d0][m] = v.x; centT[d0 + 1][m] = v.y;
    centT[d0 + 2][m] = v.z; centT[d0 + 3][m] = v.w;
  }
  __syncthreads();
  float dot = 0.f;
#pragma unroll
  for (int d = 0; d < 64; d++) dot += qs[wave][d] * centT[d][lane];
  float val = dot * SCALE;
  for (int r = 0; r < KL; r++) {
    float v = val;
    int id = lane;
#pragma unroll
    for (int off = 32; off; off >>= 1) {
      float ov = __shfl_xor(v, off, 64);
      int oi = __shfl_xor(id, off, 64);
      if (ov > v || (ov == v && oi < id)) { v = ov; id = oi; }
    }
    if (lane == 0) topk[qi * KL + r] = id;
    if (lane == id) val = -INFINITY;
  }
}

// ---------------------------------------------------------------------------
// Sparse attention (byte-identical to R4's passing version).
// ---------------------------------------------------------------------------
__global__ __launch_bounds__(256) void attn_kernel(
    const float* __restrict__ qb, const float* __restrict__ kb,
    const float* __restrict__ vb, const int* __restrict__ topk,
    unsigned short* __restrict__ ao2)
{
  __shared__ float probs[4][128];
  int tid = threadIdx.x;
  int wave = tid >> 6, lane = tid & 63;
  int qi = (blockIdx.x << 2) + wave;
  int h = qi >> 11, n = qi & 2047;
  int4 tk = *(const int4*)(topk + qi * KL);
  int segArr[4] = {tk.x, tk.y, tk.z, tk.w};
  const float* qrow = qb + (size_t)qi * DH;
  float4 qreg[4];
#pragma unroll
  for (int i = 0; i < 4; i++)
    qreg[i] = *(const float4*)(qrow + ((lane & 3) + 4 * i) * 4);

  float e[8];
  float score[8];
#pragma unroll
  for (int g = 0; g < 8; g++) {
    int seg = segArr[g >> 1];
    int key_n = seg * SEG + (lane >> 2) + 16 * (g & 1);
    const float* krow = kb + ((size_t)(h << 11) + key_n) * DH;
    float acc = 0.f;
#pragma unroll
    for (int i = 0; i < 4; i++) {
      float4 kv = *(const float4*)(krow + ((lane & 3) + 4 * i) * 4);
      float4 qv = qreg[i];
      acc += qv.x * kv.x + qv.y * kv.y + qv.z * kv.z + qv.w * kv.w;
    }
    acc += __shfl_xor(acc, 1, 64);
    acc += __shfl_xor(acc, 2, 64);
    score[g] = acc * SCALE;
  }
  float mx = score[0];
#pragma unroll
  for (int g = 1; g < 8; g++) mx = fmaxf(mx, score[g]);
#pragma unroll
  for (int off = 4; off < 64; off <<= 1) mx = fmaxf(mx, __shfl_xor(mx, off, 64));
  float ls = 0.f;
#pragma unroll
  for (int g = 0; g < 8; g++) { e[g] = expf(score[g] - mx); ls += e[g]; }
#pragma unroll
  for (int off = 4; off < 64; off <<= 1) ls += __shfl_xor(ls, off, 64);
  float inv = 1.0f / ls;
  if ((lane & 3) == 0) {
#pragma unroll
    for (int g = 0; g < 8; g++) probs[wave][(lane >> 2) + 16 * g] = e[g] * inv;
  }
  __syncthreads();

  float o = 0.f;
#pragma unroll
  for (int si = 0; si < KL; si++) {
    int seg = segArr[si];
    const float* vrow = vb + ((size_t)(h << 11) + seg * SEG) * DH + lane;
#pragma unroll
    for (int ss = 0; ss < SEG; ss++) o += probs[wave][(si << 5) + ss] * vrow[(size_t)ss * DH];
  }
  unsigned short hb = f2bf(o);
  float lo = o - bf2f(hb);
  ao2[(size_t)n * 1024 + (h << 6) + lane] = hb;
  ao2[(size_t)n * 1024 + 512 + (h << 6) + lane] = f2bf(lo);
}

// ---------------------------------------------------------------------------
extern "C" void kernel_launch(void* const* d_in, const int* in_sizes, int n_in,
                              void* d_out, int out_size, void* d_ws, size_t ws_size,
                              hipStream_t stream)
{
  const float* x      = (const float*)d_in[0];   // (1,2048,512)
  const float* w_qkv  = (const float*)d_in[1];   // (1536,512)
  const float* w_proj = (const float*)d_in[2];   // (512,512)
  const float* b_proj = (const float*)d_in[3];   // (512,)
  float* out = (float*)d_out;                    // (1,2048,512)

  float* base = (float*)d_ws;
  float* qbuf = base;                                   // 1,048,576 f
  float* kbuf = base + 1048576;
  float* vbuf = base + 2097152;
  float* cent = base + 3145728;                         // 32,768 f
  int*   topk = (int*)(base + 3178496);                 // 65,536 i
  unsigned short* X2  = (unsigned short*)(base + 3244032);  // 2048x1024 bf16 (2-term)
  unsigned short* W2v = (unsigned short*)(base + 4292608);  // 512x1024  (V rows of w_qkv)
  unsigned short* WP2 = (unsigned short*)(base + 4554752);  // 512x1024  (w_proj)
  unsigned short* AO2 = X2;  // overlay: X2 dead after V GEMM

  // 1. fused 2-term bf16 splits (x, V-rows of w_qkv, w_proj)
  split3_kernel<<<6144, 256, 0, stream>>>(x, w_qkv + 1024 * 512, w_proj,
                                          X2, W2v, WP2);
  // 2. Q/K via fp32 gemm_qk — bit-identical chain to R0 (route path frozen)
  {
    dim3 grid(1024 / 64, N_TOK / 64);
    gemm_qk<<<grid, 256, 0, stream>>>(x, w_qkv, qbuf, kbuf);
  }
  // 3. V via bf16-split MFMA (continuous path)
  {
    dim3 grid(512 / 64, N_TOK / 64);
    gemm_mfma<<<grid, 256, 0, stream>>>(X2, W2v, vbuf, nullptr, nullptr, 0, 0);
  }
  // 4. centroids (from bit-exact k)
  centroid_kernel<<<(H_NUM * M_LM * DH) / 256, 256, 0, stream>>>(kbuf, cent);
  // 5. route + top-4 (bit-exact scores vs R0)
  route_topk_kernel<<<(H_NUM * N_TOK) / 4, 256, 0, stream>>>(qbuf, cent, topk);
  // 6. sparse attention -> 2-term AO2 (overlays X2)
  attn_kernel<<<(H_NUM * N_TOK) / 4, 256, 0, stream>>>(qbuf, kbuf, vbuf, topk, AO2);
  // 7. proj GEMM (MFMA, 3 products) + bias
  {
    dim3 grid(C_DIM / 64, N_TOK / 64);
    gemm_mfma<<<grid, 256, 0, stream>>>(AO2, WP2, nullptr, out, b_proj, C_DIM, 1);
  }
}